// Round 8
// baseline (315.908 us; speedup 1.0000x reference)
//
#include <hip/hip_runtime.h>
#include <stdint.h>

typedef unsigned short u16;
typedef __attribute__((ext_vector_type(8))) short short8;
typedef __attribute__((ext_vector_type(4))) float floatx4;

#define DEV __device__ __forceinline__

DEV u16 f2bf(float f) {  // RNE
  union { float f; unsigned u; } x; x.f = f;
  unsigned u = x.u + 0x7fffu + ((x.u >> 16) & 1u);
  return (u16)(u >> 16);
}
DEV float scrub(float x) {
  return fminf(fmaxf(x, -65504.0f), 65504.0f);
}
DEV void async16(const void* g, void* l) {
  auto gp = reinterpret_cast<const __attribute__((address_space(1))) unsigned int*>(
      reinterpret_cast<uintptr_t>(g));
  auto lp = reinterpret_cast<__attribute__((address_space(3))) unsigned int*>(
      reinterpret_cast<uintptr_t>(l));
  __builtin_amdgcn_global_load_lds(gp, lp, 16, 0, 0);
}
DEV unsigned asu(float f) { union { float f; unsigned u; } x; x.f = f; return x.u; }
DEV float asf(unsigned u) { union { unsigned u; float f; } x; x.u = u; return x.f; }

// ===========================================================================
// fp32 -> bf16 elementwise convert (RNE), 4 elems/thread.
// Single fused kernel: z 0..2 activations (n4a), z 3..6 weights (n4w).
// ===========================================================================
__global__ void cvt7(const float* __restrict__ a, const float* __restrict__ b,
                     const float* __restrict__ c, const float* __restrict__ w0,
                     const float* __restrict__ w1, const float* __restrict__ w2,
                     const float* __restrict__ w3,
                     u16* __restrict__ oa, u16* __restrict__ ob, u16* __restrict__ oc,
                     u16* __restrict__ o0, u16* __restrict__ o1, u16* __restrict__ o2,
                     u16* __restrict__ o3,
                     int n4a, int n4w) {
  int z = blockIdx.z;
  const float* s;
  u16* d;
  int n4;
  switch (z) {
    case 0: s = a;  d = oa; n4 = n4a; break;
    case 1: s = b;  d = ob; n4 = n4a; break;
    case 2: s = c;  d = oc; n4 = n4a; break;
    case 3: s = w0; d = o0; n4 = n4w; break;
    case 4: s = w1; d = o1; n4 = n4w; break;
    case 5: s = w2; d = o2; n4 = n4w; break;
    default: s = w3; d = o3; n4 = n4w; break;
  }
  int i = blockIdx.x * 256 + threadIdx.x;
  if (i < n4) {
    float4 v = ((const float4*)s)[i];
    union { u16 h[4]; uint2 u; } o;
    o.h[0] = f2bf(v.x); o.h[1] = f2bf(v.y); o.h[2] = f2bf(v.z); o.h[3] = f2bf(v.w);
    ((uint2*)d)[i] = o.u;
  }
}

// ===========================================================================
// Projection GEMM (bf16 NT, 128x128 tile, BK=64) — v2: DOUBLE-BUFFERED LDS
// (attn3's schedule: stage next tile before compute, single vmcnt(0)+barrier
// per K-step instead of stage->drain->barrier->compute->barrier).
// z=0 (Q): C^T orient, out head-split (B,H,L,DK), prescaled SCALE*log2e.
// z=1 (K): C^T orient, head-split.
// z=2 (V): C orient, out transposed head-split (B,H,DK,L).
// XCD-aware block swizzle for X-panel L2 reuse.
// ===========================================================================
__global__ __launch_bounds__(256, 2) void proj3(
    const u16* __restrict__ Xq, const u16* __restrict__ Xk, const u16* __restrict__ Xv,
    const u16* __restrict__ Wq, const u16* __restrict__ Wk, const u16* __restrict__ Wv,
    u16* __restrict__ Oq, u16* __restrict__ Ok, u16* __restrict__ Ov)
{
  constexpr int K = 1024;
  constexpr float SC2 = 0.125f * 1.44269504088896f;
  // grid (8,64,3), nwg=1536 (%8==0): bijective XCD swizzle
  int flat = blockIdx.x + 8 * (blockIdx.y + 64 * blockIdx.z);
  int swz = (flat & 7) * 192 + (flat >> 3);
  const int bx = swz & 7, by = (swz >> 3) & 63, z = swz >> 9;

  const u16* X = z == 0 ? Xq : (z == 1 ? Xk : Xv);
  const u16* W = z == 0 ? Wq : (z == 1 ? Wk : Wv);
  u16* Out = z == 0 ? Oq : (z == 1 ? Ok : Ov);

  const u16* A = (z < 2) ? W : X;
  const u16* Bp = (z < 2) ? X : W;
  const int m0 = (z < 2) ? bx * 128 : by * 128;
  const int n0 = (z < 2) ? by * 128 : bx * 128;

  const int tid = threadIdx.x;
  const int w = tid >> 6, lane = tid & 63;
  const int quad = lane >> 4, l16 = lane & 15;
  const int wm = (w & 1) * 64, wn = (w >> 1) * 64;

  // 64 KiB: A_p at SM[p*8192], B_p at SM[16384 + p*8192] (u16 elements)
  __shared__ u16 SM[32768];

  auto stage = [&](int p, int k0) {
#pragma unroll
    for (int i = 0; i < 4; ++i) {
      int lin = i * 256 + tid;
      int r = lin >> 3, sp = lin & 7, s = sp ^ (r & 7);
      async16(A + (size_t)(m0 + r) * K + k0 + s * 8, &SM[p * 8192 + lin * 8]);
    }
#pragma unroll
    for (int i = 0; i < 4; ++i) {
      int lin = i * 256 + tid;
      int r = lin >> 3, sp = lin & 7, s = sp ^ (r & 7);
      async16(Bp + (size_t)(n0 + r) * K + k0 + s * 8, &SM[16384 + p * 8192 + lin * 8]);
    }
  };

  floatx4 acc[4][4];
#pragma unroll
  for (int i = 0; i < 4; ++i)
#pragma unroll
    for (int j = 0; j < 4; ++j) acc[i][j] = (floatx4)0.0f;

  stage(0, 0);
  asm volatile("s_waitcnt vmcnt(0)" ::: "memory");
  __syncthreads();

  for (int k0 = 0; k0 < K; k0 += 64) {
    const int p = (k0 >> 6) & 1;
    if (k0 + 64 < K) stage(p ^ 1, k0 + 64);
    const u16* Asp = &SM[p * 8192];
    const u16* Bsp = &SM[16384 + p * 8192];

    __builtin_amdgcn_s_setprio(1);
#pragma unroll
    for (int kk = 0; kk < 2; ++kk) {
      short8 af[4], bf[4];
#pragma unroll
      for (int mi = 0; mi < 4; ++mi) {
        int r = wm + mi * 16 + l16;
        af[mi] = *(const short8*)&Asp[r * 64 + (((kk * 4 + quad) ^ (r & 7)) * 8)];
      }
#pragma unroll
      for (int ni = 0; ni < 4; ++ni) {
        int r = wn + ni * 16 + l16;
        bf[ni] = *(const short8*)&Bsp[r * 64 + (((kk * 4 + quad) ^ (r & 7)) * 8)];
      }
#pragma unroll
      for (int mi = 0; mi < 4; ++mi)
#pragma unroll
        for (int ni = 0; ni < 4; ++ni)
          acc[mi][ni] = __builtin_amdgcn_mfma_f32_16x16x32_bf16(af[mi], bf[ni], acc[mi][ni], 0, 0, 0);
    }
    __builtin_amdgcn_s_setprio(0);

    asm volatile("s_waitcnt vmcnt(0)" ::: "memory");
    __syncthreads();
  }

  const float sc = (z == 0) ? SC2 : 1.0f;
#pragma unroll
  for (int mi = 0; mi < 4; ++mi) {
#pragma unroll
    for (int ni = 0; ni < 4; ++ni) {
      int rr = m0 + wm + mi * 16 + quad * 4;
      int cc = n0 + wn + ni * 16 + l16;
      u16 h0 = f2bf(sc * acc[mi][ni][0]);
      u16 h1 = f2bf(sc * acc[mi][ni][1]);
      u16 h2 = f2bf(sc * acc[mi][ni][2]);
      u16 h3 = f2bf(sc * acc[mi][ni][3]);
      uint2 dw; dw.x = h0 | ((unsigned)h1 << 16); dw.y = h2 | ((unsigned)h3 << 16);
      if (z < 2) {
        int bb = cc >> 11, ll = cc & 2047;
        int hh = rr >> 6, dk0 = rr & 63;
        *(uint2*)&Out[(((size_t)bb * 16 + hh) * 2048 + ll) * 64 + dk0] = dw;
      } else {
        int bb = rr >> 11, ll0 = rr & 2047;
        int hh = cc >> 6, dk = cc & 63;
        *(uint2*)&Out[(((size_t)bb * 16 + hh) * 64 + dk) * 2048 + ll0] = dw;
      }
    }
  }
}

// ===========================================================================
// Output GEMM: C[M,N] = A[M,K]*W[N,K]^T — v2: double-buffered LDS (same
// schedule as proj3 v2). A bf16 head-split, W bf16, C fp32 row-major.
// XCD-aware swizzle (A-panel reuse).
// ===========================================================================
__global__ __launch_bounds__(256, 2) void gemm_out(
    const u16* __restrict__ Ah, const u16* __restrict__ Wo, float* __restrict__ Out)
{
  constexpr int K = 1024;
  const int tid = threadIdx.x;
  const int w = tid >> 6, lane = tid & 63;
  const int quad = lane >> 4, l16 = lane & 15;
  // grid (8,64), nwg=512 (%8==0): bijective XCD swizzle
  int flat = blockIdx.x + 8 * blockIdx.y;
  int swz = (flat & 7) * 64 + (flat >> 3);
  const int bx = swz & 7, by = swz >> 3;
  const int m0 = by * 128, n0 = bx * 128;
  const int wm = (w & 1) * 64, wn = (w >> 1) * 64;

  __shared__ u16 SM[32768];

  auto stage = [&](int p, int k0) {
#pragma unroll
    for (int i = 0; i < 4; ++i) {
      int lin = i * 256 + tid;
      int r = lin >> 3, sp = lin & 7, s = sp ^ (r & 7);
      int row = m0 + r;  // head-split A: k-tile == head
      const u16* ga = Ah + (((size_t)(row >> 11) * 16 + (k0 >> 6)) * 2048 + (row & 2047)) * 64 + s * 8;
      async16(ga, &SM[p * 8192 + lin * 8]);
    }
#pragma unroll
    for (int i = 0; i < 4; ++i) {
      int lin = i * 256 + tid;
      int r = lin >> 3, sp = lin & 7, s = sp ^ (r & 7);
      async16(Wo + (size_t)(n0 + r) * K + k0 + s * 8, &SM[16384 + p * 8192 + lin * 8]);
    }
  };

  floatx4 acc[4][4];
#pragma unroll
  for (int i = 0; i < 4; ++i)
#pragma unroll
    for (int j = 0; j < 4; ++j) acc[i][j] = (floatx4)0.0f;

  stage(0, 0);
  asm volatile("s_waitcnt vmcnt(0)" ::: "memory");
  __syncthreads();

  for (int k0 = 0; k0 < K; k0 += 64) {
    const int p = (k0 >> 6) & 1;
    if (k0 + 64 < K) stage(p ^ 1, k0 + 64);
    const u16* Asp = &SM[p * 8192];
    const u16* Bsp = &SM[16384 + p * 8192];

    __builtin_amdgcn_s_setprio(1);
#pragma unroll
    for (int kk = 0; kk < 2; ++kk) {
      short8 af[4], bf[4];
#pragma unroll
      for (int mi = 0; mi < 4; ++mi) {
        int r = wm + mi * 16 + l16;
        af[mi] = *(const short8*)&Asp[r * 64 + (((kk * 4 + quad) ^ (r & 7)) * 8)];
      }
#pragma unroll
      for (int ni = 0; ni < 4; ++ni) {
        int r = wn + ni * 16 + l16;
        bf[ni] = *(const short8*)&Bsp[r * 64 + (((kk * 4 + quad) ^ (r & 7)) * 8)];
      }
#pragma unroll
      for (int mi = 0; mi < 4; ++mi)
#pragma unroll
        for (int ni = 0; ni < 4; ++ni)
          acc[mi][ni] = __builtin_amdgcn_mfma_f32_16x16x32_bf16(af[mi], bf[ni], acc[mi][ni], 0, 0, 0);
    }
    __builtin_amdgcn_s_setprio(0);

    asm volatile("s_waitcnt vmcnt(0)" ::: "memory");
    __syncthreads();
  }

#pragma unroll
  for (int mi = 0; mi < 4; ++mi)
#pragma unroll
    for (int ni = 0; ni < 4; ++ni) {
      int rr = m0 + wm + mi * 16 + quad * 4;
      int cc = n0 + wn + ni * 16 + l16;
#pragma unroll
      for (int reg = 0; reg < 4; ++reg)
        Out[(size_t)(rr + reg) * 1024 + cc] = scrub(acc[mi][ni][reg]);
    }
}

// ===========================================================================
// Flash attention v8 (full-tile S cluster for MFMA ILP):
// grid (L/128, H, B) flattened + XCD swizzle, 256 threads.
// S^T for ALL 4 key-tiles in one MFMA cluster, kk-outer (8 indep chains).
// Fixed-shift softmax (P = exp2(S'), l via ones-MFMA), v_perm bf16 pack.
// ===========================================================================
__global__ __launch_bounds__(256, 4) void attn3(
    const u16* Qh, const u16* __restrict__ Kh,
    const u16* __restrict__ VT, u16* O)
{
  constexpr int L = 2048, DK = 64, H = 16;
  const int tid = threadIdx.x;
  const int w = tid >> 6, lane = tid & 63;
  const int quad = lane >> 4, l16 = lane & 15;
  // nwg = 16*16*4 = 1024 (%8==0): bijective XCD swizzle.
  int flat = blockIdx.x + 16 * (blockIdx.y + 16 * blockIdx.z);
  int swz = (flat & 7) * 128 + (flat >> 3);
  const int q0 = (swz & 15) * 128;
  const int bh = swz >> 4;          // = b*H + h

  // 32 KiB flat: buf0 at byte 0, buf1 at byte 16384. K half at +0 (8KB),
  // V half at +8192 bytes. Q staging (16KB) overlays buf1.
  __shared__ u16 SM[4 * 64 * 64];
  u16* const QP = &SM[8192];
  char* const SMb = (char*)&SM[0];

  const u16* Qg = Qh + ((size_t)bh * L + q0) * DK;
  const u16* Kb = Kh + (size_t)bh * L * DK;
  const u16* Vb = VT + (size_t)bh * DK * L;  // rows = dk, length L

  // ---- Q staging into QP (= buf1 overlay) ----
#pragma unroll
  for (int i = 0; i < 4; ++i) {
    int lin = i * 256 + tid;
    int r = lin >> 3, sp = lin & 7, s = sp ^ (r & 7);
    async16(Qg + (size_t)r * DK + s * 8, &QP[lin * 8]);
  }

  // ---- persistent per-lane staging pointers ----
  const int rA = tid >> 3;
  const int sA = (tid & 7) ^ (rA & 7);
  const u16* kg0 = Kb + (size_t)rA * DK + sA * 8;
  const u16* kg1 = kg0 + 32 * DK;                 // rows 32..63
  const u16* vg0 = Vb + (size_t)rA * L + sA * 8;
  const u16* vg1 = vg0 + (size_t)32 * L;
  u16* const ldsB0 = &SM[tid * 8];
  u16* const ldsB1 = &SM[8192 + tid * 8];

  // stage tile 0 into buf0
  async16(kg0, ldsB0);
  async16(kg1, ldsB0 + 2048);
  async16(vg0, ldsB0 + 4096);
  async16(vg1, ldsB0 + 6144);
  kg0 += 64 * DK; kg1 += 64 * DK; vg0 += 64; vg1 += 64;

  asm volatile("s_waitcnt vmcnt(0)" ::: "memory");
  __syncthreads();

  short8 qf[2][2];
#pragma unroll
  for (int mi = 0; mi < 2; ++mi)
#pragma unroll
    for (int kk = 0; kk < 2; ++kk) {
      int r = w * 32 + mi * 16 + l16;
      qf[mi][kk] = *(const short8*)&QP[r * 64 + (((kk * 4 + quad) ^ (r & 7)) * 8)];
    }
  // All waves must finish reading Q before buf1 (= QP) is first staged.
  asm volatile("s_waitcnt lgkmcnt(0)" ::: "memory");
  __syncthreads();

  // ---- hoisted per-lane LDS byte offsets (r&7 == l16&7 for all tiles) ----
  const int l7 = l16 & 7, qh2 = quad >> 1, qo = (quad & 1) * 8;
  int ka[2], vo[4];
#pragma unroll
  for (int kk = 0; kk < 2; ++kk)
    ka[kk] = l16 * 128 + (((kk * 4 + quad) ^ l7) * 16);
#pragma unroll
  for (int j = 0; j < 4; ++j)
    vo[j] = l16 * 128 + (((qh2 + 2 * j) ^ l7) * 16) + qo;

  short8 onesv;
#pragma unroll
  for (int j = 0; j < 8; ++j) onesv[j] = (short)0x3F80;  // bf16 1.0

  floatx4 oT[4][2];   // [dk-tile][q-tile]
  floatx4 lacc[2];    // l accumulator (row 0 used)
#pragma unroll
  for (int nd = 0; nd < 4; ++nd)
#pragma unroll
    for (int mi = 0; mi < 2; ++mi) oT[nd][mi] = (floatx4)0.0f;
  lacc[0] = (floatx4)0.0f;
  lacc[1] = (floatx4)0.0f;

  auto body = [&](int PB, u16* ldsN, bool more) {
    if (more) {
      async16(kg0, ldsN);
      async16(kg1, ldsN + 2048);
      async16(vg0, ldsN + 4096);
      async16(vg1, ldsN + 6144);
      kg0 += 64 * DK; kg1 += 64 * DK; vg0 += 64; vg1 += 64;
    }

    // ---- S^T = K Q^T, all 4 key-tiles, kk-outer (8 indep chains) ----
    floatx4 sT[4][2];
#pragma unroll
    for (int t = 0; t < 4; ++t)
#pragma unroll
      for (int mi = 0; mi < 2; ++mi) sT[t][mi] = (floatx4)0.0f;
    __builtin_amdgcn_s_setprio(1);
#pragma unroll
    for (int kk = 0; kk < 2; ++kk)
#pragma unroll
      for (int t = 0; t < 4; ++t) {
        short8 kf = *(const short8*)(SMb + PB + t * 2048 + ka[kk]);
#pragma unroll
        for (int mi = 0; mi < 2; ++mi)
          sT[t][mi] = __builtin_amdgcn_mfma_f32_16x16x32_bf16(kf, qf[mi][kk], sT[t][mi], 0, 0, 0);
      }
    __builtin_amdgcn_s_setprio(0);

    // ---- P = exp2(S') (fixed shift 0), raw v_exp_f32 ----
#pragma unroll
    for (int t = 0; t < 4; ++t)
#pragma unroll
      for (int mi = 0; mi < 2; ++mi)
#pragma unroll
        for (int r = 0; r < 4; ++r) sT[t][mi][r] = __builtin_amdgcn_exp2f(sT[t][mi][r]);

    // ---- pack to bf16 B-frags via v_perm (trunc) for both groups ----
    short8 pf[2][2];   // [g][mi]
#pragma unroll
    for (int g = 0; g < 2; ++g)
#pragma unroll
      for (int mi = 0; mi < 2; ++mi) {
        union { unsigned u[4]; short8 v; } up;
        up.u[0] = __builtin_amdgcn_perm(asu(sT[2 * g][mi][1]), asu(sT[2 * g][mi][0]), 0x07060302u);
        up.u[1] = __builtin_amdgcn_perm(asu(sT[2 * g][mi][3]), asu(sT[2 * g][mi][2]), 0x07060302u);
        up.u[2] = __builtin_amdgcn_perm(asu(sT[2 * g + 1][mi][1]), asu(sT[2 * g + 1][mi][0]), 0x07060302u);
        up.u[3] = __builtin_amdgcn_perm(asu(sT[2 * g + 1][mi][3]), asu(sT[2 * g + 1][mi][2]), 0x07060302u);
        pf[g][mi] = up.v;
      }

    // ---- O^T += V^T P^T ; l += ones . P^T (same accumulation order) ----
    __builtin_amdgcn_s_setprio(1);
#pragma unroll
    for (int g = 0; g < 2; ++g) {
#pragma unroll
      for (int nd = 0; nd < 4; ++nd) {
        union { uint2 ab[2]; short8 v; } uv;
        uv.ab[0] = *(const uint2*)(SMb + PB + 8192 + nd * 2048 + vo[2 * g]);
        uv.ab[1] = *(const uint2*)(SMb + PB + 8192 + nd * 2048 + vo[2 * g + 1]);
#pragma unroll
        for (int mi = 0; mi < 2; ++mi)
          oT[nd][mi] = __builtin_amdgcn_mfma_f32_16x16x32_bf16(uv.v, pf[g][mi], oT[nd][mi], 0, 0, 0);
      }
#pragma unroll
      for (int mi = 0; mi < 2; ++mi)
        lacc[mi] = __builtin_amdgcn_mfma_f32_16x16x32_bf16(onesv, pf[g][mi], lacc[mi], 0, 0, 0);
    }
    __builtin_amdgcn_s_setprio(0);

    asm volatile("s_waitcnt vmcnt(0)" ::: "memory");
    __syncthreads();
  };

  for (int j0 = 0; j0 < L; j0 += 128) {
    // pin hoisted offsets live (defeat remat under occupancy heuristic)
    asm volatile("" : "+v"(ka[0]), "+v"(ka[1]),
                      "+v"(vo[0]), "+v"(vo[1]), "+v"(vo[2]), "+v"(vo[3]));
    body(0, ldsB1, true);                 // compute tile j0 (buf0), stage j0+64
    body(16384, ldsB0, j0 + 128 < L);     // compute tile j0+64 (buf1), stage j0+128
  }

  // ---- epilogue: O^T lane holds dk=nd*16+quad*4+r at token col l16 ----
#pragma unroll
  for (int mi = 0; mi < 2; ++mi) {
    float inv = 1.0f / fmaxf(lacc[mi][0], 1e-30f);
    int token = q0 + w * 32 + mi * 16 + l16;
#pragma unroll
    for (int nd = 0; nd < 4; ++nd) {
      u16 h0 = f2bf(scrub(oT[nd][mi][0] * inv));
      u16 h1 = f2bf(scrub(oT[nd][mi][1] * inv));
      u16 h2 = f2bf(scrub(oT[nd][mi][2] * inv));
      u16 h3 = f2bf(scrub(oT[nd][mi][3] * inv));
      uint2 dw; dw.x = h0 | ((unsigned)h1 << 16); dw.y = h2 | ((unsigned)h3 << 16);
      *(uint2*)&O[((size_t)bh * L + token) * 64 + nd * 16 + quad * 4] = dw;
    }
  }
}

// ===========================================================================
extern "C" void kernel_launch(void* const* d_in, const int* in_sizes, int n_in,
                              void* d_out, int out_size, void* d_ws, size_t ws_size,
                              hipStream_t stream) {
  const float* q  = (const float*)d_in[0];
  const float* k  = (const float*)d_in[1];
  const float* v  = (const float*)d_in[2];
  const float* wq = (const float*)d_in[3];
  const float* wk = (const float*)d_in[4];
  const float* wv = (const float*)d_in[5];
  const float* wo = (const float*)d_in[6];
  float* out = (float*)d_out;

  const size_t NE = (size_t)4 * 16 * 2048 * 64;  // 8388608
  const size_t WN = (size_t)1024 * 1024;

  u16* qb  = (u16*)d_ws;
  u16* kb  = qb + NE;
  u16* vb  = kb + NE;
  u16* wqb = vb + NE;
  u16* wkb = wqb + WN;
  u16* wvb = wkb + WN;
  u16* wob = wvb + WN;
  u16* Qh  = wob + WN;          // Q head-split (prescaled); attn overwrites it
  u16* Kh  = (u16*)d_out;       // K head-split in d_out (dead before final)
  u16* VTg = Kh + NE;           // V^T (B,H,DK,L)

  int n4a = (int)(NE / 4), n4w = (int)(WN / 4);
  cvt7<<<dim3((n4a + 255) / 256, 1, 7), 256, 0, stream>>>(
      q, k, v, wq, wk, wv, wo, qb, kb, vb, wqb, wkb, wvb, wob, n4a, n4w);

  dim3 g1(8, 64, 3);
  proj3<<<g1, dim3(256), 0, stream>>>(qb, kb, vb, wqb, wkb, wvb, Qh, Kh, VTg);

  dim3 g2(16, 16, 4);
  attn3<<<g2, dim3(256), 0, stream>>>(Qh, Kh, VTg, Qh);

  dim3 g3(8, 64, 1);
  gemm_out<<<g3, dim3(256), 0, stream>>>(Qh, wob, out);
}

// Round 9
// 305.531 us; speedup vs baseline: 1.0340x; 1.0340x over previous
//
#include <hip/hip_runtime.h>
#include <stdint.h>

typedef unsigned short u16;
typedef __attribute__((ext_vector_type(8))) short short8;
typedef __attribute__((ext_vector_type(4))) float floatx4;

#define DEV __device__ __forceinline__

DEV u16 f2bf(float f) {  // RNE
  union { float f; unsigned u; } x; x.f = f;
  unsigned u = x.u + 0x7fffu + ((x.u >> 16) & 1u);
  return (u16)(u >> 16);
}
DEV float scrub(float x) {
  return fminf(fmaxf(x, -65504.0f), 65504.0f);
}
DEV void async16(const void* g, void* l) {
  auto gp = reinterpret_cast<const __attribute__((address_space(1))) unsigned int*>(
      reinterpret_cast<uintptr_t>(g));
  auto lp = reinterpret_cast<__attribute__((address_space(3))) unsigned int*>(
      reinterpret_cast<uintptr_t>(l));
  __builtin_amdgcn_global_load_lds(gp, lp, 16, 0, 0);
}
DEV unsigned asu(float f) { union { float f; unsigned u; } x; x.f = f; return x.u; }
DEV float asf(unsigned u) { union { unsigned u; float f; } x; x.u = u; return x.f; }

// ===========================================================================
// fp32 -> bf16 convert (RNE), 4 elems/thread, EXACT flat grid (no idle
// blocks: activations are 3 x 2^21 float4s, weights 4 x 2^18 -> shift/mask
// tensor select). 28672 blocks total vs 57344 (half no-op) before.
// ===========================================================================
__global__ void cvt7(const float* __restrict__ a, const float* __restrict__ b,
                     const float* __restrict__ c, const float* __restrict__ w0,
                     const float* __restrict__ w1, const float* __restrict__ w2,
                     const float* __restrict__ w3,
                     u16* __restrict__ oa, u16* __restrict__ ob, u16* __restrict__ oc,
                     u16* __restrict__ o0, u16* __restrict__ o1, u16* __restrict__ o2,
                     u16* __restrict__ o3) {
  constexpr int N4A = 1 << 21;   // 8388608/4
  constexpr int N4W = 1 << 18;   // 1048576/4
  int i4 = blockIdx.x * 256 + threadIdx.x;
  const float* s;
  u16* d;
  int off;
  if (i4 < 3 * N4A) {
    int z = i4 >> 21;
    off = i4 & (N4A - 1);
    s = z == 0 ? a : (z == 1 ? b : c);
    d = z == 0 ? oa : (z == 1 ? ob : oc);
  } else {
    int j = i4 - 3 * N4A;
    int z = j >> 18;
    off = j & (N4W - 1);
    s = z == 0 ? w0 : (z == 1 ? w1 : (z == 2 ? w2 : w3));
    d = z == 0 ? o0 : (z == 1 ? o1 : (z == 2 ? o2 : o3));
  }
  float4 v = ((const float4*)s)[off];
  union { u16 h[4]; uint2 u; } o;
  o.h[0] = f2bf(v.x); o.h[1] = f2bf(v.y); o.h[2] = f2bf(v.z); o.h[3] = f2bf(v.w);
  ((uint2*)d)[off] = o.u;
}

// ===========================================================================
// Projection GEMM (bf16 NT, m97 structure, 128x128 tile, BK=64) — v3:
// SINGLE-BUFFERED 32KB LDS + __launch_bounds__(256,4) -> 4 blocks/CU
// (was pinned at 2). The m97 structure hides barrier drains via multi-block
// co-residency (m114); dbuf at 2/CU was proven neutral (R8).
// z=0 (Q): C^T orient, out head-split (B,H,L,DK), prescaled SCALE*log2e.
// z=1 (K): C^T orient, head-split.
// z=2 (V): C orient, out transposed head-split (B,H,DK,L).
// XCD-aware block swizzle for X-panel L2 reuse.
// ===========================================================================
__global__ __launch_bounds__(256, 4) void proj3(
    const u16* __restrict__ Xq, const u16* __restrict__ Xk, const u16* __restrict__ Xv,
    const u16* __restrict__ Wq, const u16* __restrict__ Wk, const u16* __restrict__ Wv,
    u16* __restrict__ Oq, u16* __restrict__ Ok, u16* __restrict__ Ov)
{
  constexpr int K = 1024;
  constexpr float SC2 = 0.125f * 1.44269504088896f;
  // grid (8,64,3), nwg=1536 (%8==0): bijective XCD swizzle
  int flat = blockIdx.x + 8 * (blockIdx.y + 64 * blockIdx.z);
  int swz = (flat & 7) * 192 + (flat >> 3);
  const int bx = swz & 7, by = (swz >> 3) & 63, z = swz >> 9;

  const u16* X = z == 0 ? Xq : (z == 1 ? Xk : Xv);
  const u16* W = z == 0 ? Wq : (z == 1 ? Wk : Wv);
  u16* Out = z == 0 ? Oq : (z == 1 ? Ok : Ov);

  const u16* A = (z < 2) ? W : X;
  const u16* Bp = (z < 2) ? X : W;
  const int m0 = (z < 2) ? bx * 128 : by * 128;
  const int n0 = (z < 2) ? by * 128 : bx * 128;

  const int tid = threadIdx.x;
  const int w = tid >> 6, lane = tid & 63;
  const int quad = lane >> 4, l16 = lane & 15;
  const int wm = (w & 1) * 64, wn = (w >> 1) * 64;

  __shared__ u16 As[128 * 64];
  __shared__ u16 Bs[128 * 64];

  floatx4 acc[4][4];
#pragma unroll
  for (int i = 0; i < 4; ++i)
#pragma unroll
    for (int j = 0; j < 4; ++j) acc[i][j] = (floatx4)0.0f;

  for (int k0 = 0; k0 < K; k0 += 64) {
#pragma unroll
    for (int i = 0; i < 4; ++i) {
      int lin = i * 256 + tid;
      int r = lin >> 3, sp = lin & 7, s = sp ^ (r & 7);
      async16(A + (size_t)(m0 + r) * K + k0 + s * 8, &As[lin * 8]);
    }
#pragma unroll
    for (int i = 0; i < 4; ++i) {
      int lin = i * 256 + tid;
      int r = lin >> 3, sp = lin & 7, s = sp ^ (r & 7);
      async16(Bp + (size_t)(n0 + r) * K + k0 + s * 8, &Bs[lin * 8]);
    }
    asm volatile("s_waitcnt vmcnt(0)" ::: "memory");
    __syncthreads();

#pragma unroll
    for (int kk = 0; kk < 2; ++kk) {
      short8 af[4], bf[4];
#pragma unroll
      for (int mi = 0; mi < 4; ++mi) {
        int r = wm + mi * 16 + l16;
        af[mi] = *(const short8*)&As[r * 64 + (((kk * 4 + quad) ^ (r & 7)) * 8)];
      }
#pragma unroll
      for (int ni = 0; ni < 4; ++ni) {
        int r = wn + ni * 16 + l16;
        bf[ni] = *(const short8*)&Bs[r * 64 + (((kk * 4 + quad) ^ (r & 7)) * 8)];
      }
#pragma unroll
      for (int mi = 0; mi < 4; ++mi)
#pragma unroll
        for (int ni = 0; ni < 4; ++ni)
          acc[mi][ni] = __builtin_amdgcn_mfma_f32_16x16x32_bf16(af[mi], bf[ni], acc[mi][ni], 0, 0, 0);
    }
    __syncthreads();
  }

  const float sc = (z == 0) ? SC2 : 1.0f;
#pragma unroll
  for (int mi = 0; mi < 4; ++mi) {
#pragma unroll
    for (int ni = 0; ni < 4; ++ni) {
      int rr = m0 + wm + mi * 16 + quad * 4;
      int cc = n0 + wn + ni * 16 + l16;
      u16 h0 = f2bf(sc * acc[mi][ni][0]);
      u16 h1 = f2bf(sc * acc[mi][ni][1]);
      u16 h2 = f2bf(sc * acc[mi][ni][2]);
      u16 h3 = f2bf(sc * acc[mi][ni][3]);
      uint2 dw; dw.x = h0 | ((unsigned)h1 << 16); dw.y = h2 | ((unsigned)h3 << 16);
      if (z < 2) {
        int bb = cc >> 11, ll = cc & 2047;
        int hh = rr >> 6, dk0 = rr & 63;
        *(uint2*)&Out[(((size_t)bb * 16 + hh) * 2048 + ll) * 64 + dk0] = dw;
      } else {
        int bb = rr >> 11, ll0 = rr & 2047;
        int hh = cc >> 6, dk = cc & 63;
        *(uint2*)&Out[(((size_t)bb * 16 + hh) * 64 + dk) * 2048 + ll0] = dw;
      }
    }
  }
}

// ===========================================================================
// Output GEMM: C[M,N] = A[M,K]*W[N,K]^T — double-buffered (grid 512 caps at
// 2 blocks/CU regardless, so dbuf+2/CU retained). A bf16 head-split, W bf16,
// C fp32 row-major. XCD-aware swizzle (A-panel reuse).
// ===========================================================================
__global__ __launch_bounds__(256, 2) void gemm_out(
    const u16* __restrict__ Ah, const u16* __restrict__ Wo, float* __restrict__ Out)
{
  constexpr int K = 1024;
  const int tid = threadIdx.x;
  const int w = tid >> 6, lane = tid & 63;
  const int quad = lane >> 4, l16 = lane & 15;
  // grid (8,64), nwg=512 (%8==0): bijective XCD swizzle
  int flat = blockIdx.x + 8 * blockIdx.y;
  int swz = (flat & 7) * 64 + (flat >> 3);
  const int bx = swz & 7, by = swz >> 3;
  const int m0 = by * 128, n0 = bx * 128;
  const int wm = (w & 1) * 64, wn = (w >> 1) * 64;

  __shared__ u16 SM[32768];

  auto stage = [&](int p, int k0) {
#pragma unroll
    for (int i = 0; i < 4; ++i) {
      int lin = i * 256 + tid;
      int r = lin >> 3, sp = lin & 7, s = sp ^ (r & 7);
      int row = m0 + r;  // head-split A: k-tile == head
      const u16* ga = Ah + (((size_t)(row >> 11) * 16 + (k0 >> 6)) * 2048 + (row & 2047)) * 64 + s * 8;
      async16(ga, &SM[p * 8192 + lin * 8]);
    }
#pragma unroll
    for (int i = 0; i < 4; ++i) {
      int lin = i * 256 + tid;
      int r = lin >> 3, sp = lin & 7, s = sp ^ (r & 7);
      async16(Wo + (size_t)(n0 + r) * K + k0 + s * 8, &SM[16384 + p * 8192 + lin * 8]);
    }
  };

  floatx4 acc[4][4];
#pragma unroll
  for (int i = 0; i < 4; ++i)
#pragma unroll
    for (int j = 0; j < 4; ++j) acc[i][j] = (floatx4)0.0f;

  stage(0, 0);
  asm volatile("s_waitcnt vmcnt(0)" ::: "memory");
  __syncthreads();

  for (int k0 = 0; k0 < K; k0 += 64) {
    const int p = (k0 >> 6) & 1;
    if (k0 + 64 < K) stage(p ^ 1, k0 + 64);
    const u16* Asp = &SM[p * 8192];
    const u16* Bsp = &SM[16384 + p * 8192];

    __builtin_amdgcn_s_setprio(1);
#pragma unroll
    for (int kk = 0; kk < 2; ++kk) {
      short8 af[4], bf[4];
#pragma unroll
      for (int mi = 0; mi < 4; ++mi) {
        int r = wm + mi * 16 + l16;
        af[mi] = *(const short8*)&Asp[r * 64 + (((kk * 4 + quad) ^ (r & 7)) * 8)];
      }
#pragma unroll
      for (int ni = 0; ni < 4; ++ni) {
        int r = wn + ni * 16 + l16;
        bf[ni] = *(const short8*)&Bsp[r * 64 + (((kk * 4 + quad) ^ (r & 7)) * 8)];
      }
#pragma unroll
      for (int mi = 0; mi < 4; ++mi)
#pragma unroll
        for (int ni = 0; ni < 4; ++ni)
          acc[mi][ni] = __builtin_amdgcn_mfma_f32_16x16x32_bf16(af[mi], bf[ni], acc[mi][ni], 0, 0, 0);
    }
    __builtin_amdgcn_s_setprio(0);

    asm volatile("s_waitcnt vmcnt(0)" ::: "memory");
    __syncthreads();
  }

#pragma unroll
  for (int mi = 0; mi < 4; ++mi)
#pragma unroll
    for (int ni = 0; ni < 4; ++ni) {
      int rr = m0 + wm + mi * 16 + quad * 4;
      int cc = n0 + wn + ni * 16 + l16;
#pragma unroll
      for (int reg = 0; reg < 4; ++reg)
        Out[(size_t)(rr + reg) * 1024 + cc] = scrub(acc[mi][ni][reg]);
    }
}

// ===========================================================================
// Flash attention v8 (full-tile S cluster for MFMA ILP):
// grid (L/128, H, B) flattened + XCD swizzle, 256 threads.
// S^T for ALL 4 key-tiles in one MFMA cluster, kk-outer (8 indep chains).
// Fixed-shift softmax (P = exp2(S'), l via ones-MFMA), v_perm bf16 pack.
// ===========================================================================
__global__ __launch_bounds__(256, 4) void attn3(
    const u16* Qh, const u16* __restrict__ Kh,
    const u16* __restrict__ VT, u16* O)
{
  constexpr int L = 2048, DK = 64, H = 16;
  const int tid = threadIdx.x;
  const int w = tid >> 6, lane = tid & 63;
  const int quad = lane >> 4, l16 = lane & 15;
  // nwg = 16*16*4 = 1024 (%8==0): bijective XCD swizzle.
  int flat = blockIdx.x + 16 * (blockIdx.y + 16 * blockIdx.z);
  int swz = (flat & 7) * 128 + (flat >> 3);
  const int q0 = (swz & 15) * 128;
  const int bh = swz >> 4;          // = b*H + h

  // 32 KiB flat: buf0 at byte 0, buf1 at byte 16384. K half at +0 (8KB),
  // V half at +8192 bytes. Q staging (16KB) overlays buf1.
  __shared__ u16 SM[4 * 64 * 64];
  u16* const QP = &SM[8192];
  char* const SMb = (char*)&SM[0];

  const u16* Qg = Qh + ((size_t)bh * L + q0) * DK;
  const u16* Kb = Kh + (size_t)bh * L * DK;
  const u16* Vb = VT + (size_t)bh * DK * L;  // rows = dk, length L

  // ---- Q staging into QP (= buf1 overlay) ----
#pragma unroll
  for (int i = 0; i < 4; ++i) {
    int lin = i * 256 + tid;
    int r = lin >> 3, sp = lin & 7, s = sp ^ (r & 7);
    async16(Qg + (size_t)r * DK + s * 8, &QP[lin * 8]);
  }

  // ---- persistent per-lane staging pointers ----
  const int rA = tid >> 3;
  const int sA = (tid & 7) ^ (rA & 7);
  const u16* kg0 = Kb + (size_t)rA * DK + sA * 8;
  const u16* kg1 = kg0 + 32 * DK;                 // rows 32..63
  const u16* vg0 = Vb + (size_t)rA * L + sA * 8;
  const u16* vg1 = vg0 + (size_t)32 * L;
  u16* const ldsB0 = &SM[tid * 8];
  u16* const ldsB1 = &SM[8192 + tid * 8];

  // stage tile 0 into buf0
  async16(kg0, ldsB0);
  async16(kg1, ldsB0 + 2048);
  async16(vg0, ldsB0 + 4096);
  async16(vg1, ldsB0 + 6144);
  kg0 += 64 * DK; kg1 += 64 * DK; vg0 += 64; vg1 += 64;

  asm volatile("s_waitcnt vmcnt(0)" ::: "memory");
  __syncthreads();

  short8 qf[2][2];
#pragma unroll
  for (int mi = 0; mi < 2; ++mi)
#pragma unroll
    for (int kk = 0; kk < 2; ++kk) {
      int r = w * 32 + mi * 16 + l16;
      qf[mi][kk] = *(const short8*)&QP[r * 64 + (((kk * 4 + quad) ^ (r & 7)) * 8)];
    }
  // All waves must finish reading Q before buf1 (= QP) is first staged.
  asm volatile("s_waitcnt lgkmcnt(0)" ::: "memory");
  __syncthreads();

  // ---- hoisted per-lane LDS byte offsets (r&7 == l16&7 for all tiles) ----
  const int l7 = l16 & 7, qh2 = quad >> 1, qo = (quad & 1) * 8;
  int ka[2], vo[4];
#pragma unroll
  for (int kk = 0; kk < 2; ++kk)
    ka[kk] = l16 * 128 + (((kk * 4 + quad) ^ l7) * 16);
#pragma unroll
  for (int j = 0; j < 4; ++j)
    vo[j] = l16 * 128 + (((qh2 + 2 * j) ^ l7) * 16) + qo;

  short8 onesv;
#pragma unroll
  for (int j = 0; j < 8; ++j) onesv[j] = (short)0x3F80;  // bf16 1.0

  floatx4 oT[4][2];   // [dk-tile][q-tile]
  floatx4 lacc[2];    // l accumulator (row 0 used)
#pragma unroll
  for (int nd = 0; nd < 4; ++nd)
#pragma unroll
    for (int mi = 0; mi < 2; ++mi) oT[nd][mi] = (floatx4)0.0f;
  lacc[0] = (floatx4)0.0f;
  lacc[1] = (floatx4)0.0f;

  auto body = [&](int PB, u16* ldsN, bool more) {
    if (more) {
      async16(kg0, ldsN);
      async16(kg1, ldsN + 2048);
      async16(vg0, ldsN + 4096);
      async16(vg1, ldsN + 6144);
      kg0 += 64 * DK; kg1 += 64 * DK; vg0 += 64; vg1 += 64;
    }

    // ---- S^T = K Q^T, all 4 key-tiles, kk-outer (8 indep chains) ----
    floatx4 sT[4][2];
#pragma unroll
    for (int t = 0; t < 4; ++t)
#pragma unroll
      for (int mi = 0; mi < 2; ++mi) sT[t][mi] = (floatx4)0.0f;
    __builtin_amdgcn_s_setprio(1);
#pragma unroll
    for (int kk = 0; kk < 2; ++kk)
#pragma unroll
      for (int t = 0; t < 4; ++t) {
        short8 kf = *(const short8*)(SMb + PB + t * 2048 + ka[kk]);
#pragma unroll
        for (int mi = 0; mi < 2; ++mi)
          sT[t][mi] = __builtin_amdgcn_mfma_f32_16x16x32_bf16(kf, qf[mi][kk], sT[t][mi], 0, 0, 0);
      }
    __builtin_amdgcn_s_setprio(0);

    // ---- P = exp2(S') (fixed shift 0), raw v_exp_f32 ----
#pragma unroll
    for (int t = 0; t < 4; ++t)
#pragma unroll
      for (int mi = 0; mi < 2; ++mi)
#pragma unroll
        for (int r = 0; r < 4; ++r) sT[t][mi][r] = __builtin_amdgcn_exp2f(sT[t][mi][r]);

    // ---- pack to bf16 B-frags via v_perm (trunc) for both groups ----
    short8 pf[2][2];   // [g][mi]
#pragma unroll
    for (int g = 0; g < 2; ++g)
#pragma unroll
      for (int mi = 0; mi < 2; ++mi) {
        union { unsigned u[4]; short8 v; } up;
        up.u[0] = __builtin_amdgcn_perm(asu(sT[2 * g][mi][1]), asu(sT[2 * g][mi][0]), 0x07060302u);
        up.u[1] = __builtin_amdgcn_perm(asu(sT[2 * g][mi][3]), asu(sT[2 * g][mi][2]), 0x07060302u);
        up.u[2] = __builtin_amdgcn_perm(asu(sT[2 * g + 1][mi][1]), asu(sT[2 * g + 1][mi][0]), 0x07060302u);
        up.u[3] = __builtin_amdgcn_perm(asu(sT[2 * g + 1][mi][3]), asu(sT[2 * g + 1][mi][2]), 0x07060302u);
        pf[g][mi] = up.v;
      }

    // ---- O^T += V^T P^T ; l += ones . P^T (same accumulation order) ----
    __builtin_amdgcn_s_setprio(1);
#pragma unroll
    for (int g = 0; g < 2; ++g) {
#pragma unroll
      for (int nd = 0; nd < 4; ++nd) {
        union { uint2 ab[2]; short8 v; } uv;
        uv.ab[0] = *(const uint2*)(SMb + PB + 8192 + nd * 2048 + vo[2 * g]);
        uv.ab[1] = *(const uint2*)(SMb + PB + 8192 + nd * 2048 + vo[2 * g + 1]);
#pragma unroll
        for (int mi = 0; mi < 2; ++mi)
          oT[nd][mi] = __builtin_amdgcn_mfma_f32_16x16x32_bf16(uv.v, pf[g][mi], oT[nd][mi], 0, 0, 0);
      }
#pragma unroll
      for (int mi = 0; mi < 2; ++mi)
        lacc[mi] = __builtin_amdgcn_mfma_f32_16x16x32_bf16(onesv, pf[g][mi], lacc[mi], 0, 0, 0);
    }
    __builtin_amdgcn_s_setprio(0);

    asm volatile("s_waitcnt vmcnt(0)" ::: "memory");
    __syncthreads();
  };

  for (int j0 = 0; j0 < L; j0 += 128) {
    // pin hoisted offsets live (defeat remat under occupancy heuristic)
    asm volatile("" : "+v"(ka[0]), "+v"(ka[1]),
                      "+v"(vo[0]), "+v"(vo[1]), "+v"(vo[2]), "+v"(vo[3]));
    body(0, ldsB1, true);                 // compute tile j0 (buf0), stage j0+64
    body(16384, ldsB0, j0 + 128 < L);     // compute tile j0+64 (buf1), stage j0+128
  }

  // ---- epilogue: O^T lane holds dk=nd*16+quad*4+r at token col l16 ----
#pragma unroll
  for (int mi = 0; mi < 2; ++mi) {
    float inv = 1.0f / fmaxf(lacc[mi][0], 1e-30f);
    int token = q0 + w * 32 + mi * 16 + l16;
#pragma unroll
    for (int nd = 0; nd < 4; ++nd) {
      u16 h0 = f2bf(scrub(oT[nd][mi][0] * inv));
      u16 h1 = f2bf(scrub(oT[nd][mi][1] * inv));
      u16 h2 = f2bf(scrub(oT[nd][mi][2] * inv));
      u16 h3 = f2bf(scrub(oT[nd][mi][3] * inv));
      uint2 dw; dw.x = h0 | ((unsigned)h1 << 16); dw.y = h2 | ((unsigned)h3 << 16);
      *(uint2*)&O[((size_t)bh * L + token) * 64 + nd * 16 + quad * 4] = dw;
    }
  }
}

// ===========================================================================
extern "C" void kernel_launch(void* const* d_in, const int* in_sizes, int n_in,
                              void* d_out, int out_size, void* d_ws, size_t ws_size,
                              hipStream_t stream) {
  const float* q  = (const float*)d_in[0];
  const float* k  = (const float*)d_in[1];
  const float* v  = (const float*)d_in[2];
  const float* wq = (const float*)d_in[3];
  const float* wk = (const float*)d_in[4];
  const float* wv = (const float*)d_in[5];
  const float* wo = (const float*)d_in[6];
  float* out = (float*)d_out;

  const size_t NE = (size_t)4 * 16 * 2048 * 64;  // 8388608
  const size_t WN = (size_t)1024 * 1024;

  u16* qb  = (u16*)d_ws;
  u16* kb  = qb + NE;
  u16* vb  = kb + NE;
  u16* wqb = vb + NE;
  u16* wkb = wqb + WN;
  u16* wvb = wkb + WN;
  u16* wob = wvb + WN;
  u16* Qh  = wob + WN;          // Q head-split (prescaled); attn overwrites it
  u16* Kh  = (u16*)d_out;       // K head-split in d_out (dead before final)
  u16* VTg = Kh + NE;           // V^T (B,H,DK,L)

  // exact flat grid: (3*2^21 + 4*2^18)/256 = 28672 blocks
  cvt7<<<dim3(28672), 256, 0, stream>>>(
      q, k, v, wq, wk, wv, wo, qb, kb, vb, wqb, wkb, wvb, wob);

  dim3 g1(8, 64, 3);
  proj3<<<g1, dim3(256), 0, stream>>>(qb, kb, vb, wqb, wkb, wvb, Qh, Kh, VTg);

  dim3 g2(16, 16, 4);
  attn3<<<g2, dim3(256), 0, stream>>>(Qh, Kh, VTg, Qh);

  dim3 g3(8, 64, 1);
  gemm_out<<<g3, dim3(256), 0, stream>>>(Qh, wob, out);
}